// Round 2
// baseline (233.465 us; speedup 1.0000x reference)
//
#include <hip/hip_runtime.h>
#include <math.h>

// Problem constants
#define NN 8
#define C_TOTAL 448
#define CC 100
#define HH 56
#define WW 56
#define HW (HH*WW)          // 3136
#define NPIX4 (HW/4)        // 784 quads (float4 pixel groups)
#define OH 224
#define OW 224
#define NT4 13              // ceil(784/64) quad tiles
#define NK 50               // adjacent-row pairs: rows (2k, 2k+1)

typedef __attribute__((ext_vector_type(4))) _Float16 half4;
typedef __attribute__((ext_vector_type(8))) _Float16 half8;
typedef __attribute__((ext_vector_type(4))) float    f32x4;

__device__ __forceinline__ f32x4 cvtlo(const half8 h) {
    return __builtin_convertvector(__builtin_shufflevector(h, h, 0, 1, 2, 3), f32x4);
}
__device__ __forceinline__ f32x4 cvthi(const half8 h) {
    return __builtin_convertvector(__builtin_shufflevector(h, h, 4, 5, 6, 7), f32x4);
}
__device__ __forceinline__ f32x4 fmav(const f32x4 a, const f32x4 b, const f32x4 c) {
    f32x4 r;
    r.x = fmaf(a.x, b.x, c.x);
    r.y = fmaf(a.y, b.y, c.y);
    r.z = fmaf(a.z, b.z, c.z);
    r.w = fmaf(a.w, b.w, c.w);
    return r;
}

// ---------------------------------------------------------------------------
// Kernel 0: x -> fp16, TRANSPOSED layout xbuf[c][quad][n] (half4 elements).
// One thread per (c, quad); loops n internally; writes one contiguous 64 B run.
// Also zeroes the smap accumulator (first NN*NPIX4 threads).
// ---------------------------------------------------------------------------
__global__ __launch_bounds__(256) void prep_x_kernel(
    const float* __restrict__ fmaps, const int* __restrict__ sel,
    const float* __restrict__ mean, half4* __restrict__ xbuf,
    float* __restrict__ smap)
{
    const int idx = blockIdx.x * 256 + threadIdx.x;
    if (idx < NN * NPIX4) {
        ((float4*)smap)[idx] = make_float4(0.f, 0.f, 0.f, 0.f);
    }
    if (idx >= CC * NPIX4) return;
    const int quad = idx % NPIX4;
    const int c    = idx / NPIX4;

    const float4* f4 = (const float4*)fmaps;
    const float4  m  = ((const float4*)mean)[(size_t)c * NPIX4 + quad];
    const int     sc = sel[c];

    half4 hv[NN];
#pragma unroll
    for (int n = 0; n < NN; ++n) {
        const float4 f = f4[((size_t)n * C_TOTAL + sc) * NPIX4 + quad];
        half4 h;
        h.x = (_Float16)(f.x - m.x);
        h.y = (_Float16)(f.y - m.y);
        h.z = (_Float16)(f.z - m.z);
        h.w = (_Float16)(f.w - m.w);
        hv[n] = h;
    }
    half4* dst = xbuf + ((size_t)c * NPIX4 + quad) * NN;   // 64 B contiguous
#pragma unroll
    for (int n = 0; n < NN; ++n) dst[n] = hv[n];
}

// ---------------------------------------------------------------------------
// Kernel 1: adjacent-row pair (a=2k, b=2k+1); occupancy-oriented layout:
//   256 threads = 4 waves = (2 d-phases) x (2 image-halves), d-stride 2.
//   Each (pair, tile) is split across 2 blocks covering half the d-range
//   each -> 1300 blocks, ~all co-resident at ~5 blocks/CU (LDS now 16 KB).
//   One x[d] load feeds FMAs for BOTH cov rows (upper-triangle symmetry,
//   diag weight 0.5; contribution = 2*(x_a.acc_a + x_b.acc_b)).
//   cov is loaded NON-TEMPORALLY (touched exactly once globally) so the
//   5 MB xbuf stays L2-resident for the 50x cross-block reuse.
//   Cross-wave sum via 16 KB LDS dump + barrier, then atomicAdd into smap
//   (linear in blocks, so the d-split needs no extra reduction pass).
// ---------------------------------------------------------------------------
__global__ __launch_bounds__(256, 5) void qform_kernel(
    const half4* __restrict__ xbuf, const float* __restrict__ cov,
    float* __restrict__ smap)
{
    __shared__ f32x4 lred[4 * 4 * 64];   // [wave][img][lane] = 16 KB

    const int tile = blockIdx.x % NT4;
    const int rest = blockIdx.x / NT4;
    const int h    = rest & 1;           // d-range half
    const int k    = rest >> 1;          // 0..49 (k ascending -> long blocks first)
    const int a    = 2 * k;
    const int b    = a + 1;

    const int w    = threadIdx.x >> 6;   // wave id 0..3
    const int dph  = w & 1;              // d phase
    const int nh   = w >> 1;             // image half (0: n=0..3, 1: n=4..7)
    const int lane = threadIdx.x & 63;
    const int qraw = tile * 64 + lane;
    const bool valid = qraw < NPIX4;
    const int quad = valid ? qraw : (NPIX4 - 1);   // clamp, no early return

    const int L   = CC - a;
    const int mid = a + ((L + 1) >> 1);
    const int dlo = h ? mid : a;
    const int dhi = h ? CC  : mid;

    const f32x4* c4 = (const f32x4*)cov;

    f32x4 acca[4], accb[4];
#pragma unroll
    for (int i = 0; i < 4; ++i) {
        acca[i] = (f32x4){0.f, 0.f, 0.f, 0.f};
        accb[i] = (f32x4){0.f, 0.f, 0.f, 0.f};
    }

    for (int d = dlo + dph; d < dhi; d += 2) {
        const half8* xp = (const half8*)(xbuf + ((size_t)d * NPIX4 + quad) * NN + nh * 4);
        const half8 hA = xp[0];          // images nh*4+0, nh*4+1
        const half8 hB = xp[1];          // images nh*4+2, nh*4+3
        f32x4 xv[4];
        xv[0] = cvtlo(hA); xv[1] = cvthi(hA);
        xv[2] = cvtlo(hB); xv[3] = cvthi(hB);

        f32x4 cva = __builtin_nontemporal_load(&c4[((size_t)a * CC + d) * NPIX4 + quad]);
        if (d == a) cva *= 0.5f;
#pragma unroll
        for (int i = 0; i < 4; ++i) acca[i] = fmav(xv[i], cva, acca[i]);

        if (d > a) {                     // d >= b (wave-uniform branch)
            f32x4 cvb = __builtin_nontemporal_load(&c4[((size_t)b * CC + d) * NPIX4 + quad]);
            if (d == b) cvb *= 0.5f;
#pragma unroll
            for (int i = 0; i < 4; ++i) accb[i] = fmav(xv[i], cvb, accb[i]);
        }
    }

    // fold: part[i] = 2*(x_a[i]*acc_a[i] + x_b[i]*acc_b[i]); dump to LDS
    {
        const half8* xap = (const half8*)(xbuf + ((size_t)a * NPIX4 + quad) * NN + nh * 4);
        const half8* xbp = (const half8*)(xbuf + ((size_t)b * NPIX4 + quad) * NN + nh * 4);
        const half8 xa0 = xap[0], xa1 = xap[1];
        const half8 xb0 = xbp[0], xb1 = xbp[1];
        f32x4 xa[4], xb[4];
        xa[0] = cvtlo(xa0); xa[1] = cvthi(xa0); xa[2] = cvtlo(xa1); xa[3] = cvthi(xa1);
        xb[0] = cvtlo(xb0); xb[1] = cvthi(xb0); xb[2] = cvtlo(xb1); xb[3] = cvthi(xb1);
#pragma unroll
        for (int i = 0; i < 4; ++i) {
            f32x4 t = xa[i] * acca[i];
            t = fmav(xb[i], accb[i], t);
            t = t + t;                   // x2
            lred[(w * 4 + i) * 64 + lane] = t;
        }
    }
    __syncthreads();

    // final: wave w handles global images {2w, 2w+1}; sum the 2 d-phase partials
#pragma unroll
    for (int j = 0; j < 2; ++j) {
        const int im  = 2 * w + j;
        const int nhh = im >> 2;
        const int sl  = im & 3;
        const f32x4 s0 = lred[((nhh * 2 + 0) * 4 + sl) * 64 + lane];
        const f32x4 s1 = lred[((nhh * 2 + 1) * 4 + sl) * 64 + lane];
        const f32x4 s  = s0 + s1;
        if (valid) {
            float* dst = smap + (size_t)im * HW + (size_t)qraw * 4;
            atomicAdd(dst + 0, s.x);
            atomicAdd(dst + 1, s.y);
            atomicAdd(dst + 2, s.z);
            atomicAdd(dst + 3, s.w);
        }
    }
}

// ---------------------------------------------------------------------------
// Kernel 2: sqrt + bilinear x4 upsample (half-pixel, edge clamp) + normalize
// ---------------------------------------------------------------------------
__global__ __launch_bounds__(256) void upsample_kernel(
    const float* __restrict__ smap,
    const float* __restrict__ minp, const float* __restrict__ maxp,
    float* __restrict__ out)
{
    const int idx = blockIdx.x * 256 + threadIdx.x;
    const int total = NN * OH * OW;
    if (idx >= total) return;

    const int ox = idx % OW;
    const int oy = (idx / OW) % OH;
    const int n  = idx / (OW * OH);

    const float fy = oy * 0.25f - 0.375f;
    const float fx = ox * 0.25f - 0.375f;

    int y0 = (int)floorf(fy);
    int x0 = (int)floorf(fx);
    const float wy = fy - (float)y0;
    const float wx = fx - (float)x0;
    int y1 = min(y0 + 1, HH - 1); y0 = max(y0, 0);
    int x1 = min(x0 + 1, WW - 1); x0 = max(x0, 0);

    const float* s = smap + (size_t)n * HW;
    const float v00 = sqrtf(fmaxf(s[y0 * WW + x0], 0.f));
    const float v01 = sqrtf(fmaxf(s[y0 * WW + x1], 0.f));
    const float v10 = sqrtf(fmaxf(s[y1 * WW + x0], 0.f));
    const float v11 = sqrtf(fmaxf(s[y1 * WW + x1], 0.f));

    const float v = (1.0f - wy) * ((1.0f - wx) * v00 + wx * v01)
                  +          wy * ((1.0f - wx) * v10 + wx * v11);

    const float mn = *minp;
    const float mx = *maxp;
    out[idx] = (v - mn) / (mx - mn);
}

// ---------------------------------------------------------------------------
extern "C" void kernel_launch(void* const* d_in, const int* in_sizes, int n_in,
                              void* d_out, int out_size, void* d_ws, size_t ws_size,
                              hipStream_t stream)
{
    const float* fmaps = (const float*)d_in[0];
    const int*   sel   = (const int*)  d_in[1];
    const float* mean  = (const float*)d_in[2];
    const float* cov   = (const float*)d_in[3];
    const float* minp  = (const float*)d_in[4];
    const float* maxp  = (const float*)d_in[5];
    float* out = (float*)d_out;

    half4* xbuf = (half4*)d_ws;                                   // CC*NPIX4*NN half4 = 5.0 MB
    float* smap = (float*)((char*)d_ws + (size_t)CC*NPIX4*NN*8);  // NN*HW f32 = 0.1 MB (atomic acc)

    {
        const int total = CC * NPIX4;
        prep_x_kernel<<<(total + 255) / 256, 256, 0, stream>>>(fmaps, sel, mean, xbuf, smap);
    }
    qform_kernel<<<NK * 2 * NT4, 256, 0, stream>>>(xbuf, cov, smap);
    {
        const int total = NN * OH * OW;
        upsample_kernel<<<(total + 255) / 256, 256, 0, stream>>>(smap, minp, maxp, out);
    }
}

// Round 3
// 221.792 us; speedup vs baseline: 1.0526x; 1.0526x over previous
//
#include <hip/hip_runtime.h>
#include <math.h>

// Problem constants
#define NN 8
#define C_TOTAL 448
#define CC 100
#define HH 56
#define WW 56
#define HW (HH*WW)          // 3136
#define NPIX4 (HW/4)        // 784 quads (float4 pixel groups)
#define OH 224
#define OW 224
#define NT4 13              // ceil(784/64) quad tiles
#define NG 25               // row groups of 4: block k handles rows 4k..4k+3

typedef __attribute__((ext_vector_type(4))) _Float16 half4;
typedef __attribute__((ext_vector_type(8))) _Float16 half8;
typedef __attribute__((ext_vector_type(4))) float    f32x4;

__device__ __forceinline__ f32x4 cvtlo(const half8 h) {
    return __builtin_convertvector(__builtin_shufflevector(h, h, 0, 1, 2, 3), f32x4);
}
__device__ __forceinline__ f32x4 cvthi(const half8 h) {
    return __builtin_convertvector(__builtin_shufflevector(h, h, 4, 5, 6, 7), f32x4);
}
__device__ __forceinline__ f32x4 fmav(const f32x4 a, const f32x4 b, const f32x4 c) {
    f32x4 r;
    r.x = fmaf(a.x, b.x, c.x);
    r.y = fmaf(a.y, b.y, c.y);
    r.z = fmaf(a.z, b.z, c.z);
    r.w = fmaf(a.w, b.w, c.w);
    return r;
}

// ---------------------------------------------------------------------------
// Kernel 0: x -> fp16, TRANSPOSED layout xbuf[c][quad][n] (half4 elements).
// One thread per (c, quad); loops n internally; writes one contiguous 64 B run.
// Also zeroes the smap accumulator (first NN*NPIX4 threads).
// ---------------------------------------------------------------------------
__global__ __launch_bounds__(256) void prep_x_kernel(
    const float* __restrict__ fmaps, const int* __restrict__ sel,
    const float* __restrict__ mean, half4* __restrict__ xbuf,
    float* __restrict__ smap)
{
    const int idx = blockIdx.x * 256 + threadIdx.x;
    if (idx < NN * NPIX4) {
        ((float4*)smap)[idx] = make_float4(0.f, 0.f, 0.f, 0.f);
    }
    if (idx >= CC * NPIX4) return;
    const int quad = idx % NPIX4;
    const int c    = idx / NPIX4;

    const float4* f4 = (const float4*)fmaps;
    const float4  m  = ((const float4*)mean)[(size_t)c * NPIX4 + quad];
    const int     sc = sel[c];

    half4 hv[NN];
#pragma unroll
    for (int n = 0; n < NN; ++n) {
        const float4 f = f4[((size_t)n * C_TOTAL + sc) * NPIX4 + quad];
        half4 h;
        h.x = (_Float16)(f.x - m.x);
        h.y = (_Float16)(f.y - m.y);
        h.z = (_Float16)(f.z - m.z);
        h.w = (_Float16)(f.w - m.w);
        hv[n] = h;
    }
    half4* dst = xbuf + ((size_t)c * NPIX4 + quad) * NN;   // 64 B contiguous
#pragma unroll
    for (int n = 0; n < NN; ++n) dst[n] = hv[n];
}

// ---------------------------------------------------------------------------
// Kernel 1: row-quad (a..a+3, a=4k); 512 threads = 8 waves =
//   (4 d-phases, stride 4) x (2 image-halves of 4 images each).
//   One x[d] column load feeds FMAs for FOUR cov rows (upper triangle,
//   diag weight 0.5; result = 2*sum_rows x_row . acc_row).
//   Intra-group triangle is PEELED: wave dph handles d0=a+dph for rows
//   i<=dph (diag *0.5) -> main loop is branch-free, all rows full weight.
//   cov loaded non-temporally (touched exactly once globally) to keep the
//   5 MB xbuf L2-resident across the 25x cross-block reuse.
//   Cross-wave sum via 32 KB LDS dump + barrier -> atomicAdd into smap.
//   325 blocks -> fully co-resident, no dispatch tail.
//   VGPR budget: acc 64 + xv 16 + cov 16 + addr ~16 = ~115; bounds (512,3)
//   cap ~170 -> spill-free (round-2 lesson).
// ---------------------------------------------------------------------------
__global__ __launch_bounds__(512, 3) void qform_kernel(
    const half4* __restrict__ xbuf, const float* __restrict__ cov,
    float* __restrict__ smap)
{
    __shared__ f32x4 lred[8 * 4 * 64];   // [wave][img-slot][lane] = 32 KB

    const int tile = blockIdx.x % NT4;
    const int k    = blockIdx.x / NT4;   // 0..24 (ascending -> long blocks first)
    const int a    = 4 * k;

    const int w    = threadIdx.x >> 6;   // wave id 0..7
    const int dph  = w & 3;              // d phase (stride 4)
    const int imgh = w >> 2;             // image half (0: n=0..3, 1: n=4..7)
    const int lane = threadIdx.x & 63;
    const int qraw = tile * 64 + lane;
    const bool valid = qraw < NPIX4;
    const int quad = valid ? qraw : (NPIX4 - 1);   // clamp, no early return

    const f32x4* c4 = (const f32x4*)cov;

    f32x4 acc[4][4];                     // [row i][img j]
#pragma unroll
    for (int i = 0; i < 4; ++i)
#pragma unroll
        for (int j = 0; j < 4; ++j) acc[i][j] = (f32x4){0.f, 0.f, 0.f, 0.f};

    // ---- peel d0 = a + dph: rows i <= dph, diag (i==dph) weight 0.5 ----
    {
        const int d0 = a + dph;
        const half8* xp = (const half8*)(xbuf + ((size_t)d0 * NPIX4 + quad) * NN + imgh * 4);
        const half8 hA = xp[0];
        const half8 hB = xp[1];
        f32x4 xv[4];
        xv[0] = cvtlo(hA); xv[1] = cvthi(hA);
        xv[2] = cvtlo(hB); xv[3] = cvthi(hB);
#pragma unroll
        for (int i = 0; i < 4; ++i) {
            if (i <= dph) {              // wave-uniform
                f32x4 cv = __builtin_nontemporal_load(
                    &c4[((size_t)(a + i) * CC + d0) * NPIX4 + quad]);
                if (i == dph) cv *= 0.5f;
#pragma unroll
                for (int j = 0; j < 4; ++j) acc[i][j] = fmav(xv[j], cv, acc[i][j]);
            }
        }
    }

    // ---- main loop: d = a+4+dph, step 4; branch-free, full weight ----
    for (int d = a + 4 + dph; d < CC; d += 4) {
        const half8* xp = (const half8*)(xbuf + ((size_t)d * NPIX4 + quad) * NN + imgh * 4);
        const half8 hA = xp[0];
        const half8 hB = xp[1];
        f32x4 xv[4];
        xv[0] = cvtlo(hA); xv[1] = cvthi(hA);
        xv[2] = cvtlo(hB); xv[3] = cvthi(hB);

        const size_t base = ((size_t)a * CC + d) * NPIX4 + quad;
#pragma unroll
        for (int i = 0; i < 4; ++i) {
            const f32x4 cv = __builtin_nontemporal_load(&c4[base + (size_t)i * CC * NPIX4]);
#pragma unroll
            for (int j = 0; j < 4; ++j) acc[i][j] = fmav(xv[j], cv, acc[i][j]);
        }
    }

    // ---- fold: part[j] = 2 * sum_i x_{a+i}[j] * acc[i][j]; dump to LDS ----
    {
        f32x4 part[4];
#pragma unroll
        for (int j = 0; j < 4; ++j) part[j] = (f32x4){0.f, 0.f, 0.f, 0.f};
#pragma unroll
        for (int i = 0; i < 4; ++i) {    // row-by-row to bound register pressure
            const half8* xp = (const half8*)(xbuf + ((size_t)(a + i) * NPIX4 + quad) * NN + imgh * 4);
            const half8 hA = xp[0];
            const half8 hB = xp[1];
            part[0] = fmav(cvtlo(hA), acc[i][0], part[0]);
            part[1] = fmav(cvthi(hA), acc[i][1], part[1]);
            part[2] = fmav(cvtlo(hB), acc[i][2], part[2]);
            part[3] = fmav(cvthi(hB), acc[i][3], part[3]);
        }
#pragma unroll
        for (int j = 0; j < 4; ++j) {
            part[j] = part[j] + part[j];             // x2
            lred[(w * 4 + j) * 64 + lane] = part[j];
        }
    }
    __syncthreads();

    // ---- final: wave w sums image w over its 4 d-phase partials ----
    {
        const int im = w;                // 0..7
        const int ih = im >> 2;          // image half that produced it
        const int sl = im & 3;           // slot within half
        f32x4 s = (f32x4){0.f, 0.f, 0.f, 0.f};
#pragma unroll
        for (int dp = 0; dp < 4; ++dp) {
            s = s + lred[((ih * 4 + dp) * 4 + sl) * 64 + lane];
        }
        if (valid) {
            float* dst = smap + (size_t)im * HW + (size_t)qraw * 4;
            atomicAdd(dst + 0, s.x);
            atomicAdd(dst + 1, s.y);
            atomicAdd(dst + 2, s.z);
            atomicAdd(dst + 3, s.w);
        }
    }
}

// ---------------------------------------------------------------------------
// Kernel 2: sqrt + bilinear x4 upsample (half-pixel, edge clamp) + normalize
// ---------------------------------------------------------------------------
__global__ __launch_bounds__(256) void upsample_kernel(
    const float* __restrict__ smap,
    const float* __restrict__ minp, const float* __restrict__ maxp,
    float* __restrict__ out)
{
    const int idx = blockIdx.x * 256 + threadIdx.x;
    const int total = NN * OH * OW;
    if (idx >= total) return;

    const int ox = idx % OW;
    const int oy = (idx / OW) % OH;
    const int n  = idx / (OW * OH);

    const float fy = oy * 0.25f - 0.375f;
    const float fx = ox * 0.25f - 0.375f;

    int y0 = (int)floorf(fy);
    int x0 = (int)floorf(fx);
    const float wy = fy - (float)y0;
    const float wx = fx - (float)x0;
    int y1 = min(y0 + 1, HH - 1); y0 = max(y0, 0);
    int x1 = min(x0 + 1, WW - 1); x0 = max(x0, 0);

    const float* s = smap + (size_t)n * HW;
    const float v00 = sqrtf(fmaxf(s[y0 * WW + x0], 0.f));
    const float v01 = sqrtf(fmaxf(s[y0 * WW + x1], 0.f));
    const float v10 = sqrtf(fmaxf(s[y1 * WW + x0], 0.f));
    const float v11 = sqrtf(fmaxf(s[y1 * WW + x1], 0.f));

    const float v = (1.0f - wy) * ((1.0f - wx) * v00 + wx * v01)
                  +          wy * ((1.0f - wx) * v10 + wx * v11);

    const float mn = *minp;
    const float mx = *maxp;
    out[idx] = (v - mn) / (mx - mn);
}

// ---------------------------------------------------------------------------
extern "C" void kernel_launch(void* const* d_in, const int* in_sizes, int n_in,
                              void* d_out, int out_size, void* d_ws, size_t ws_size,
                              hipStream_t stream)
{
    const float* fmaps = (const float*)d_in[0];
    const int*   sel   = (const int*)  d_in[1];
    const float* mean  = (const float*)d_in[2];
    const float* cov   = (const float*)d_in[3];
    const float* minp  = (const float*)d_in[4];
    const float* maxp  = (const float*)d_in[5];
    float* out = (float*)d_out;

    half4* xbuf = (half4*)d_ws;                                   // CC*NPIX4*NN half4 = 5.0 MB
    float* smap = (float*)((char*)d_ws + (size_t)CC*NPIX4*NN*8);  // NN*HW f32 = 0.1 MB (atomic acc)

    {
        const int total = CC * NPIX4;
        prep_x_kernel<<<(total + 255) / 256, 256, 0, stream>>>(fmaps, sel, mean, xbuf, smap);
    }
    qform_kernel<<<NG * NT4, 512, 0, stream>>>(xbuf, cov, smap);
    {
        const int total = NN * OH * OW;
        upsample_kernel<<<(total + 255) / 256, 256, 0, stream>>>(smap, minp, maxp, out);
    }
}

// Round 4
// 219.212 us; speedup vs baseline: 1.0650x; 1.0118x over previous
//
#include <hip/hip_runtime.h>
#include <math.h>

// Problem constants
#define NN 8
#define C_TOTAL 448
#define CC 100
#define HH 56
#define WW 56
#define HW (HH*WW)          // 3136
#define NPIX4 (HW/4)        // 784 quads (float4 pixel groups)
#define OH 224
#define OW 224
#define NT4 13              // ceil(784/64) quad tiles
#define NG 25               // row groups of 4: group k = rows 4k..4k+3
#define KSPLIT 12           // groups k<KSPLIT get their d-range split in 2 blocks
#define NKIND (2*KSPLIT + (NG - KSPLIT))   // 37 block kinds per tile

typedef __attribute__((ext_vector_type(4))) _Float16 half4;
typedef __attribute__((ext_vector_type(8))) _Float16 half8;
typedef __attribute__((ext_vector_type(4))) float    f32x4;

__device__ __forceinline__ f32x4 cvtlo(const half8 h) {
    return __builtin_convertvector(__builtin_shufflevector(h, h, 0, 1, 2, 3), f32x4);
}
__device__ __forceinline__ f32x4 cvthi(const half8 h) {
    return __builtin_convertvector(__builtin_shufflevector(h, h, 4, 5, 6, 7), f32x4);
}
__device__ __forceinline__ f32x4 fmav(const f32x4 a, const f32x4 b, const f32x4 c) {
    f32x4 r;
    r.x = fmaf(a.x, b.x, c.x);
    r.y = fmaf(a.y, b.y, c.y);
    r.z = fmaf(a.z, b.z, c.z);
    r.w = fmaf(a.w, b.w, c.w);
    return r;
}

// ---------------------------------------------------------------------------
// Kernel 0: x -> fp16, TRANSPOSED layout xbuf[c][quad][n] (half4 elements).
// Also zeroes the smap accumulator.
// ---------------------------------------------------------------------------
__global__ __launch_bounds__(256) void prep_x_kernel(
    const float* __restrict__ fmaps, const int* __restrict__ sel,
    const float* __restrict__ mean, half4* __restrict__ xbuf,
    float* __restrict__ smap)
{
    const int idx = blockIdx.x * 256 + threadIdx.x;
    if (idx < NN * NPIX4) {
        ((float4*)smap)[idx] = make_float4(0.f, 0.f, 0.f, 0.f);
    }
    if (idx >= CC * NPIX4) return;
    const int quad = idx % NPIX4;
    const int c    = idx / NPIX4;

    const float4* f4 = (const float4*)fmaps;
    const float4  m  = ((const float4*)mean)[(size_t)c * NPIX4 + quad];
    const int     sc = sel[c];

    half4 hv[NN];
#pragma unroll
    for (int n = 0; n < NN; ++n) {
        const float4 f = f4[((size_t)n * C_TOTAL + sc) * NPIX4 + quad];
        half4 h;
        h.x = (_Float16)(f.x - m.x);
        h.y = (_Float16)(f.y - m.y);
        h.z = (_Float16)(f.z - m.z);
        h.w = (_Float16)(f.w - m.w);
        hv[n] = h;
    }
    half4* dst = xbuf + ((size_t)c * NPIX4 + quad) * NN;   // 64 B contiguous
#pragma unroll
    for (int n = 0; n < NN; ++n) dst[n] = hv[n];
}

// ---------------------------------------------------------------------------
// Kernel 1: row-quad group (a..a+3, a=4k), rows SPLIT ACROSS WAVES:
//   512 threads = 8 waves = (2 row-halves rh) x (2 d-phases dph, stride 2)
//                         x (2 image-halves imgh).
//   Wave holds acc[2][4] = 32 VGPRs -> live ~110 under the (512,4) 128 cap
//   -> 2 blocks/CU, 4 waves/SIMD (R3 lesson: occupancy >> traffic).
//   Duplicate x loads between row-halves hit L1; L2/HBM x-traffic stays at
//   the G=4 level (~65 MB).
//   d-loop UNROLLED x2: 8 loads in flight per wave (latency-hiding lever).
//   Long groups (k<KSPLIT) split d-range into 2 chunk-blocks -> 481 blocks
//   of ~25..52 columns, all co-resident, no straggler block.
//   Upper-triangle symmetry with diag weight 0.5; peel handles d < r0+2.
//   cov loaded non-temporally (single-touch stream; protects xbuf L2).
//   Cross-wave sum via 32 KB LDS -> atomicAdd into smap.
// ---------------------------------------------------------------------------
__global__ __launch_bounds__(512, 4) void qform_kernel(
    const half4* __restrict__ xbuf, const float* __restrict__ cov,
    float* __restrict__ smap)
{
    __shared__ f32x4 lred[8 * 4 * 64];   // [wave][img-slot][lane] = 32 KB

    const int tile = blockIdx.x % NT4;
    const int kind = blockIdx.x / NT4;
    int k, h, split;
    if (kind < 2 * KSPLIT) { k = kind >> 1; h = kind & 1; split = 1; }
    else                   { k = kind - KSPLIT; h = 0; split = 0; }
    const int a   = 4 * k;
    const int L   = CC - a;
    const int mid = a + ((L + 1) >> 1);

    const int w    = threadIdx.x >> 6;   // wave id 0..7
    const int dph  = w & 1;              // d parity phase
    const int rh   = (w >> 1) & 1;       // row half: rows a+2rh, a+2rh+1
    const int imgh = w >> 2;             // image half (0: n=0..3, 1: n=4..7)
    const int lane = threadIdx.x & 63;
    const int qraw = tile * 64 + lane;
    const bool valid = qraw < NPIX4;
    const int quad = valid ? qraw : (NPIX4 - 1);   // clamp, no early return

    const int r0 = a + 2 * rh;
    const int r1 = r0 + 1;

    const f32x4* c4  = (const f32x4*)cov;
    const half8* xb8 = (const half8*)xbuf;
    // half8 index for column d, this quad, this image half:
    //   ((d*NPIX4 + quad)*NN + imgh*4) half4  ==  (d*NPIX4 + quad)*4 + imgh*2 half8

    f32x4 acc[2][4];                     // [row in half][img]
#pragma unroll
    for (int i = 0; i < 2; ++i)
#pragma unroll
        for (int j = 0; j < 4; ++j) acc[i][j] = (f32x4){0.f, 0.f, 0.f, 0.f};

    int lo, hi;
    if (split && h == 1) {
        // tail chunk [mid, CC), all-full rows; align start to parity (a+dph)&1
        lo = mid + (((mid ^ (a + dph)) & 1));
        hi = CC;
    } else {
        // head chunk (or full range): peel d0 = r0 + dph, then full from r0+dph+2
        hi = split ? mid : CC;
        const int d0 = r0 + dph;
        {
            const half8* xp = xb8 + ((size_t)d0 * NPIX4 + quad) * 4 + imgh * 2;
            const half8 hA = xp[0];
            const half8 hB = xp[1];
            f32x4 xv[4];
            xv[0] = cvtlo(hA); xv[1] = cvthi(hA);
            xv[2] = cvtlo(hB); xv[3] = cvthi(hB);
            f32x4 cv0 = __builtin_nontemporal_load(&c4[((size_t)r0 * CC + d0) * NPIX4 + quad]);
            if (dph == 0) {
                cv0 *= 0.5f;             // d0 == r0: diagonal of r0; r1 not touched
#pragma unroll
                for (int j = 0; j < 4; ++j) acc[0][j] = fmav(xv[j], cv0, acc[0][j]);
            } else {
                // d0 == r1: r0 full, r1 diagonal
#pragma unroll
                for (int j = 0; j < 4; ++j) acc[0][j] = fmav(xv[j], cv0, acc[0][j]);
                f32x4 cv1 = __builtin_nontemporal_load(&c4[((size_t)r1 * CC + d0) * NPIX4 + quad]);
                cv1 *= 0.5f;
#pragma unroll
                for (int j = 0; j < 4; ++j) acc[1][j] = fmav(xv[j], cv1, acc[1][j]);
            }
        }
        lo = r0 + dph + 2;
    }

    // ---- main loop, unrolled x2 (8 loads in flight), both rows full ----
    int d = lo;
    for (; d + 2 < hi; d += 4) {
        const half8* xp0 = xb8 + ((size_t)d * NPIX4 + quad) * 4 + imgh * 2;
        const half8* xp1 = xb8 + ((size_t)(d + 2) * NPIX4 + quad) * 4 + imgh * 2;
        const half8 a0 = xp0[0];
        const half8 b0 = xp0[1];
        const half8 a1 = xp1[0];
        const half8 b1 = xp1[1];
        const size_t cb0 = ((size_t)r0 * CC + d) * NPIX4 + quad;
        const size_t cb1 = ((size_t)r1 * CC + d) * NPIX4 + quad;
        const f32x4 c00 = __builtin_nontemporal_load(&c4[cb0]);
        const f32x4 c10 = __builtin_nontemporal_load(&c4[cb1]);
        const f32x4 c01 = __builtin_nontemporal_load(&c4[cb0 + 2 * NPIX4]);
        const f32x4 c11 = __builtin_nontemporal_load(&c4[cb1 + 2 * NPIX4]);

        {
            f32x4 xv[4];
            xv[0] = cvtlo(a0); xv[1] = cvthi(a0);
            xv[2] = cvtlo(b0); xv[3] = cvthi(b0);
#pragma unroll
            for (int j = 0; j < 4; ++j) acc[0][j] = fmav(xv[j], c00, acc[0][j]);
#pragma unroll
            for (int j = 0; j < 4; ++j) acc[1][j] = fmav(xv[j], c10, acc[1][j]);
        }
        {
            f32x4 xv[4];
            xv[0] = cvtlo(a1); xv[1] = cvthi(a1);
            xv[2] = cvtlo(b1); xv[3] = cvthi(b1);
#pragma unroll
            for (int j = 0; j < 4; ++j) acc[0][j] = fmav(xv[j], c01, acc[0][j]);
#pragma unroll
            for (int j = 0; j < 4; ++j) acc[1][j] = fmav(xv[j], c11, acc[1][j]);
        }
    }
    if (d < hi) {                        // tail column
        const half8* xp = xb8 + ((size_t)d * NPIX4 + quad) * 4 + imgh * 2;
        const half8 hA = xp[0];
        const half8 hB = xp[1];
        const f32x4 c0 = __builtin_nontemporal_load(&c4[((size_t)r0 * CC + d) * NPIX4 + quad]);
        const f32x4 c1 = __builtin_nontemporal_load(&c4[((size_t)r1 * CC + d) * NPIX4 + quad]);
        f32x4 xv[4];
        xv[0] = cvtlo(hA); xv[1] = cvthi(hA);
        xv[2] = cvtlo(hB); xv[3] = cvthi(hB);
#pragma unroll
        for (int j = 0; j < 4; ++j) acc[0][j] = fmav(xv[j], c0, acc[0][j]);
#pragma unroll
        for (int j = 0; j < 4; ++j) acc[1][j] = fmav(xv[j], c1, acc[1][j]);
    }

    // ---- fold: part[j] = 2*(x_r0[j]*acc0[j] + x_r1[j]*acc1[j]); LDS dump ----
    {
        const half8* x0p = xb8 + ((size_t)r0 * NPIX4 + quad) * 4 + imgh * 2;
        const half8* x1p = xb8 + ((size_t)r1 * NPIX4 + quad) * 4 + imgh * 2;
        const half8 xa0 = x0p[0], xb0 = x0p[1];
        const half8 xa1 = x1p[0], xb1 = x1p[1];
        f32x4 part[4];
        part[0] = cvtlo(xa0) * acc[0][0];
        part[1] = cvthi(xa0) * acc[0][1];
        part[2] = cvtlo(xb0) * acc[0][2];
        part[3] = cvthi(xb0) * acc[0][3];
        part[0] = fmav(cvtlo(xa1), acc[1][0], part[0]);
        part[1] = fmav(cvthi(xa1), acc[1][1], part[1]);
        part[2] = fmav(cvtlo(xb1), acc[1][2], part[2]);
        part[3] = fmav(cvthi(xb1), acc[1][3], part[3]);
#pragma unroll
        for (int j = 0; j < 4; ++j) {
            part[j] = part[j] + part[j];             // x2 (symmetry)
            lred[(w * 4 + j) * 64 + lane] = part[j];
        }
    }
    __syncthreads();

    // ---- final: wave w sums image w over its 4 (rh, dph) partials ----
    {
        const int im = w;                // 0..7
        const int sh = (im >> 2) * 4;    // source imgh base wave
        const int sl = im & 3;           // slot within image half
        f32x4 s = (f32x4){0.f, 0.f, 0.f, 0.f};
#pragma unroll
        for (int sw = 0; sw < 4; ++sw) { // (rh, dph) combos
            s = s + lred[((sh + sw) * 4 + sl) * 64 + lane];
        }
        if (valid) {
            float* dst = smap + (size_t)im * HW + (size_t)qraw * 4;
            atomicAdd(dst + 0, s.x);
            atomicAdd(dst + 1, s.y);
            atomicAdd(dst + 2, s.z);
            atomicAdd(dst + 3, s.w);
        }
    }
}

// ---------------------------------------------------------------------------
// Kernel 2: sqrt + bilinear x4 upsample (half-pixel, edge clamp) + normalize
// ---------------------------------------------------------------------------
__global__ __launch_bounds__(256) void upsample_kernel(
    const float* __restrict__ smap,
    const float* __restrict__ minp, const float* __restrict__ maxp,
    float* __restrict__ out)
{
    const int idx = blockIdx.x * 256 + threadIdx.x;
    const int total = NN * OH * OW;
    if (idx >= total) return;

    const int ox = idx % OW;
    const int oy = (idx / OW) % OH;
    const int n  = idx / (OW * OH);

    const float fy = oy * 0.25f - 0.375f;
    const float fx = ox * 0.25f - 0.375f;

    int y0 = (int)floorf(fy);
    int x0 = (int)floorf(fx);
    const float wy = fy - (float)y0;
    const float wx = fx - (float)x0;
    int y1 = min(y0 + 1, HH - 1); y0 = max(y0, 0);
    int x1 = min(x0 + 1, WW - 1); x0 = max(x0, 0);

    const float* s = smap + (size_t)n * HW;
    const float v00 = sqrtf(fmaxf(s[y0 * WW + x0], 0.f));
    const float v01 = sqrtf(fmaxf(s[y0 * WW + x1], 0.f));
    const float v10 = sqrtf(fmaxf(s[y1 * WW + x0], 0.f));
    const float v11 = sqrtf(fmaxf(s[y1 * WW + x1], 0.f));

    const float v = (1.0f - wy) * ((1.0f - wx) * v00 + wx * v01)
                  +          wy * ((1.0f - wx) * v10 + wx * v11);

    const float mn = *minp;
    const float mx = *maxp;
    out[idx] = (v - mn) / (mx - mn);
}

// ---------------------------------------------------------------------------
extern "C" void kernel_launch(void* const* d_in, const int* in_sizes, int n_in,
                              void* d_out, int out_size, void* d_ws, size_t ws_size,
                              hipStream_t stream)
{
    const float* fmaps = (const float*)d_in[0];
    const int*   sel   = (const int*)  d_in[1];
    const float* mean  = (const float*)d_in[2];
    const float* cov   = (const float*)d_in[3];
    const float* minp  = (const float*)d_in[4];
    const float* maxp  = (const float*)d_in[5];
    float* out = (float*)d_out;

    half4* xbuf = (half4*)d_ws;                                   // CC*NPIX4*NN half4 = 5.0 MB
    float* smap = (float*)((char*)d_ws + (size_t)CC*NPIX4*NN*8);  // NN*HW f32 = 0.1 MB (atomic acc)

    {
        const int total = CC * NPIX4;
        prep_x_kernel<<<(total + 255) / 256, 256, 0, stream>>>(fmaps, sel, mean, xbuf, smap);
    }
    qform_kernel<<<NKIND * NT4, 512, 0, stream>>>(xbuf, cov, smap);
    {
        const int total = NN * OH * OW;
        upsample_kernel<<<(total + 255) / 256, 256, 0, stream>>>(smap, minp, maxp, out);
    }
}